// Round 2
// baseline (394.805 us; speedup 1.0000x reference)
//
#include <hip/hip_runtime.h>
#include <hip/hip_bf16.h>
#include <stdint.h>

// Problem constants (fixed by the reference)
#define NROW 2048
#define HDIM 1024
#define VOC  50304
#define KCL  16
#define CDIM 3144   // VOC / KCL

// Tail-GEMM tiling: 64x128 tile, BK=32 (one MFMA k-step)
#define MT 64
#define NT 128
#define BK 32
#define MAXTILES 48   // sum ceil(Mk/64) <= 2048/64 + 16 = 48

// Workspace layout in 4-byte units
#define WS_SUMEXP 0            // float[2048] (zeroed each call)
#define WS_COUNTS 2048         // int[16]     (zeroed each call)
#define WS_PART   2064         // float[2048]
#define WS_ZTGT   4112         // float[2048]
#define WS_TCOL   6160         // int[2048]
#define WS_ROWS   8208         // int[16*2048]
#define WS_NTILE  40976        // int
#define WS_TILES  40977        // int[2*48] (cluster, row-tile) pairs
#define WS_XB     65536        // bf16[2048][1024]  (1048576 units)
#define WS_BT     (65536 + 1048576)  // bf16[50304][1024] (25755648 units)

typedef unsigned short u16;
typedef __attribute__((ext_vector_type(8))) short short8;
typedef __attribute__((ext_vector_type(4))) float f32x4;
typedef __attribute__((ext_vector_type(4))) unsigned short ushort4v;
typedef __attribute__((ext_vector_type(8))) unsigned short ushort8v;

__device__ __forceinline__ ushort2 f2bf2(float a, float b) {
    union { __hip_bfloat162 h; ushort2 u; } cv;
    cv.h = __float22bfloat162_rn(float2{a, b});
    return cv.u;
}

// async global->LDS, 16B per lane; LDS dest = wave-uniform base + lane*16
__device__ __forceinline__ void gload16(const void* g, void* lds) {
    __builtin_amdgcn_global_load_lds(
        (__attribute__((address_space(1))) void*)(g),
        (__attribute__((address_space(3))) void*)(lds), 16, 0, 0);
}

// ---------------------------------------------------------------------------
// Kernel 1: bucket rows by cluster, record target within-cluster column
// ---------------------------------------------------------------------------
__global__ void scatter_kernel(const int* __restrict__ y,
                               const int* __restrict__ y_pos,
                               const int* __restrict__ tip,
                               int* ws_i) {
    int n = blockIdx.x * 256 + threadIdx.x;
    if (n >= NROW) return;
    int kn = y_pos[n];
    int slot = atomicAdd(&ws_i[WS_COUNTS + kn], 1);
    ws_i[WS_ROWS + kn * NROW + slot] = n;
    ws_i[WS_TCOL + n] = tip[kn * VOC + y[n]];
}

// ---------------------------------------------------------------------------
// Kernel 1b: build compacted (cluster, row-tile) work list
// ---------------------------------------------------------------------------
__global__ void plan_kernel(int* ws_i) {
    if (threadIdx.x == 0) {
        int t = 0;
        for (int k = 0; k < KCL; k++) {
            int mk = ws_i[WS_COUNTS + k];
            int nt = (mk + MT - 1) / MT;
            for (int r = 0; r < nt; r++) {
                ws_i[WS_TILES + 2 * t]     = k;
                ws_i[WS_TILES + 2 * t + 1] = r;
                t++;
            }
        }
        ws_i[WS_NTILE] = t;
    }
}

// ---------------------------------------------------------------------------
// Kernel 2: cluster logsumexp part (fp32, tiny). One wave per row.
// ---------------------------------------------------------------------------
__global__ void cluster_kernel(const float* __restrict__ x,
                               const float* __restrict__ cw,
                               const int* __restrict__ y_pos,
                               float* ws_f) {
    int wave = threadIdx.x >> 6;
    int lane = threadIdx.x & 63;
    int n = blockIdx.x * 4 + wave;
    float acc[KCL];
#pragma unroll
    for (int k = 0; k < KCL; k++) acc[k] = 0.f;
#pragma unroll
    for (int j = 0; j < 16; j++) {
        int h = j * 64 + lane;
        float xv = x[(size_t)n * HDIM + h];
        const float4* cwr = (const float4*)(cw + (size_t)h * KCL);
#pragma unroll
        for (int q = 0; q < 4; q++) {
            float4 w = cwr[q];
            acc[q * 4 + 0] += xv * w.x;
            acc[q * 4 + 1] += xv * w.y;
            acc[q * 4 + 2] += xv * w.z;
            acc[q * 4 + 3] += xv * w.w;
        }
    }
#pragma unroll
    for (int off = 32; off >= 1; off >>= 1) {
#pragma unroll
        for (int k = 0; k < KCL; k++) acc[k] += __shfl_down(acc[k], off);
    }
    if (lane == 0) {
        int kn = y_pos[n];
        float m = acc[0];
#pragma unroll
        for (int k = 1; k < KCL; k++) m = fmaxf(m, acc[k]);
        float s = 0.f, skn = 0.f;
#pragma unroll
        for (int k = 0; k < KCL; k++) {
            s += __expf(acc[k] - m);
            skn = (k == kn) ? acc[k] : skn;
        }
        ws_f[WS_PART + n] = (m + __logf(s)) - skn;
    }
}

// ---------------------------------------------------------------------------
// Kernel 3a: x fp32 [N][H] -> bf16 [N][H]
// ---------------------------------------------------------------------------
__global__ void convx_kernel(const float* __restrict__ x, u16* __restrict__ xb) {
    int t = blockIdx.x * 256 + threadIdx.x;   // 524288 threads, 4 elems each
    float4 f = ((const float4*)x)[t];
    ushort2 a = f2bf2(f.x, f.y);
    ushort2 b = f2bf2(f.z, f.w);
    ushort4v v = {a.x, a.y, b.x, b.y};
    *(ushort4v*)(xb + (size_t)t * 4) = v;
}

// ---------------------------------------------------------------------------
// Kernel 3b: logits fp32 [H][V] -> Bt bf16 [V][H]  (tiled LDS transpose)
// ---------------------------------------------------------------------------
#define TV 128
#define TH 128
#define THP 136   // pad: row stride 272B = 17*16B (keeps b128 reads aligned)
__global__ void transpose_kernel(const float* __restrict__ L, u16* __restrict__ Bt) {
    __shared__ u16 Ls[TV * THP];
    const int v0 = blockIdx.x * TV;
    const int h0 = blockIdx.y * TH;
    const int t  = threadIdx.x;
    {
        const int vi = (t & 31) * 4;
        const int hi = t >> 5;      // 0..7
#pragma unroll
        for (int p = 0; p < 16; p++) {
            int hh = p * 8 + hi;
            float4 f = *(const float4*)(L + (size_t)(h0 + hh) * VOC + v0 + vi);
            ushort2 u01 = f2bf2(f.x, f.y);
            ushort2 u23 = f2bf2(f.z, f.w);
            Ls[(vi + 0) * THP + hh] = u01.x;
            Ls[(vi + 1) * THP + hh] = u01.y;
            Ls[(vi + 2) * THP + hh] = u23.x;
            Ls[(vi + 3) * THP + hh] = u23.y;
        }
    }
    __syncthreads();
    {
        const int hi = (t & 15) * 8;
        const int vi = t >> 4;      // 0..15
#pragma unroll
        for (int p = 0; p < 8; p++) {
            int v = p * 16 + vi;
            ushort8v val = *(const ushort8v*)&Ls[v * THP + hi];
            *(ushort8v*)(Bt + (size_t)(v0 + v) * HDIM + h0 + hi) = val;
        }
    }
}

// ---------------------------------------------------------------------------
// Kernel 4: tail GEMM, m97 structure. Tile 64x128, bf16 MFMA 16x16x32,
// global_load_lds(16B) staging for both A (gathered rows) and B.
// ---------------------------------------------------------------------------
__launch_bounds__(256, 4)
__global__ void tail_kernel(const u16* __restrict__ xb,
                            const u16* __restrict__ Bt,
                            const int* ws_i, float* ws_f) {
    __shared__ __align__(16) u16 As[MT * BK];   // [row][k] 64x32
    __shared__ __align__(16) u16 Bs[NT * BK];   // [col][k] 128x32
    __shared__ int   lrow[MT];
    __shared__ int   ltcol[MT];
    __shared__ float rowsum[MT];

    const int ntile = ws_i[WS_NTILE];
    if ((int)blockIdx.y >= ntile) return;
    const int kcl = ws_i[WS_TILES + 2 * blockIdx.y];
    const int rt  = ws_i[WS_TILES + 2 * blockIdx.y + 1];
    const int ct  = blockIdx.x;
    const int Mk  = ws_i[WS_COUNTS + kcl];

    const int tid = threadIdx.x;
    if (tid < MT) {
        int r = rt * MT + tid;
        int rid = (r < Mk) ? ws_i[WS_ROWS + kcl * NROW + r] : -1;
        lrow[tid]  = rid;
        ltcol[tid] = (rid >= 0) ? ws_i[WS_TCOL + rid] : -1;
        rowsum[tid] = 0.f;
    }
    __syncthreads();

    const int w    = tid >> 6;
    const int l    = tid & 63;
    const int quad = l >> 4;
    const int lm   = l & 15;

    // --- staging address setup (fixed per lane; advance by BK each iter) ---
    // A: wave w stages rows [16w, 16w+16): lane i -> row 16w + (i>>2), kseg i&3
    int arow = w * 16 + (l >> 2);
    int rid_s = lrow[arow]; if (rid_s < 0) rid_s = 0;      // masked in epilogue
    const u16* agp = xb + (size_t)rid_s * HDIM + (l & 3) * 8;
    u16* alds = (u16*)As + w * 512;
    // B: wave w stages cols [32w, 32w+32) in two 16-col instructions
    int c0 = w * 32 + (l >> 2);
    int c1 = c0 + 16;
    int g0 = ct * NT + c0; if (g0 >= CDIM) g0 = CDIM - 1;  // clamp last tile
    int g1 = ct * NT + c1; if (g1 >= CDIM) g1 = CDIM - 1;
    const u16* bgp0 = Bt + (size_t)(kcl * CDIM + g0) * HDIM + (l & 3) * 8;
    const u16* bgp1 = Bt + (size_t)(kcl * CDIM + g1) * HDIM + (l & 3) * 8;
    u16* blds0 = (u16*)Bs + w * 1024;
    u16* blds1 = (u16*)Bs + w * 1024 + 512;

    f32x4 acc[4][2];
#pragma unroll
    for (int mi = 0; mi < 4; mi++)
#pragma unroll
        for (int ni = 0; ni < 2; ni++) acc[mi][ni] = (f32x4)(0.f);

    for (int h0 = 0; h0 < HDIM; h0 += BK) {
        gload16(agp, alds);
        gload16(bgp0, blds0);
        gload16(bgp1, blds1);
        agp += BK; bgp0 += BK; bgp1 += BK;
        __syncthreads();   // drains vmcnt -> LDS tiles valid

        short8 a[4], b[2];
#pragma unroll
        for (int mi = 0; mi < 4; mi++)
            a[mi] = *(const short8*)&As[(mi * 16 + lm) * BK + quad * 8];
#pragma unroll
        for (int ni = 0; ni < 2; ni++)
            b[ni] = *(const short8*)&Bs[(w * 32 + ni * 16 + lm) * BK + quad * 8];
#pragma unroll
        for (int mi = 0; mi < 4; mi++)
#pragma unroll
            for (int ni = 0; ni < 2; ni++)
                acc[mi][ni] = __builtin_amdgcn_mfma_f32_16x16x32_bf16(
                    a[mi], b[ni], acc[mi][ni], 0, 0, 0);
        __syncthreads();   // frag reads done before next iter's staging
    }

    // --- epilogue: C/D layout col=lane&15, row=(lane>>4)*4+reg ---
#pragma unroll
    for (int mi = 0; mi < 4; mi++) {
#pragma unroll
        for (int r = 0; r < 4; r++) {
            int row_local = mi * 16 + quad * 4 + r;
            int rid = lrow[row_local];
            int tc  = ltcol[row_local];
            float s = 0.f;
#pragma unroll
            for (int ni = 0; ni < 2; ni++) {
                int cl = ct * NT + w * 32 + ni * 16 + lm;
                float z = acc[mi][ni][r];
                if (rid >= 0 && cl < CDIM) {
                    s += __expf(z);
                    if (cl == tc) ws_f[WS_ZTGT + rid] = z;
                }
            }
            s += __shfl_xor(s, 1);
            s += __shfl_xor(s, 2);
            s += __shfl_xor(s, 4);
            s += __shfl_xor(s, 8);
            if (lm == 0 && rid >= 0) atomicAdd(&rowsum[row_local], s);
        }
    }
    __syncthreads();
    if (tid < MT) {
        int rid = lrow[tid];
        if (rid >= 0) atomicAdd(&ws_f[WS_SUMEXP + rid], rowsum[tid]);
    }
}

// ---------------------------------------------------------------------------
// Kernel 5: nll[n] = part[n] + log(sumexp[n]) - z_target[n]
// ---------------------------------------------------------------------------
__global__ void finalize_kernel(const float* ws_f, float* __restrict__ out) {
    int n = blockIdx.x * 256 + threadIdx.x;
    if (n >= NROW) return;
    out[n] = ws_f[WS_PART + n] + __logf(ws_f[WS_SUMEXP + n]) - ws_f[WS_ZTGT + n];
}

// ---------------------------------------------------------------------------
extern "C" void kernel_launch(void* const* d_in, const int* in_sizes, int n_in,
                              void* d_out, int out_size, void* d_ws, size_t ws_size,
                              hipStream_t stream) {
    const float* x      = (const float*)d_in[0];
    const int*   y      = (const int*)d_in[1];
    const int*   y_pos  = (const int*)d_in[2];
    // d_in[3] (pos2token) is the identity partition; unused.
    const int*   tip    = (const int*)d_in[4];
    const float* cw     = (const float*)d_in[5];
    const float* logits = (const float*)d_in[6];
    float* out  = (float*)d_out;
    float* ws_f = (float*)d_ws;
    int*   ws_i = (int*)d_ws;
    u16*   xb   = (u16*)((float*)d_ws + WS_XB);
    u16*   Bt   = (u16*)((float*)d_ws + WS_BT);

    hipMemsetAsync(d_ws, 0, (size_t)(NROW + KCL) * 4, stream);

    scatter_kernel<<<NROW / 256, 256, 0, stream>>>(y, y_pos, tip, ws_i);
    plan_kernel<<<1, 64, 0, stream>>>(ws_i);
    cluster_kernel<<<NROW / 4, 256, 0, stream>>>(x, cw, y_pos, ws_f);
    convx_kernel<<<NROW * HDIM / 4 / 256, 256, 0, stream>>>(x, xb);
    transpose_kernel<<<dim3(VOC / TV, HDIM / TH), 256, 0, stream>>>(logits, Bt);

    dim3 grid((CDIM + NT - 1) / NT, MAXTILES);  // 25 x 48
    tail_kernel<<<grid, 256, 0, stream>>>(xb, Bt, ws_i, ws_f);

    finalize_kernel<<<NROW / 256, 256, 0, stream>>>(ws_f, out);
}

// Round 3
// 390.059 us; speedup vs baseline: 1.0122x; 1.0122x over previous
//
#include <hip/hip_runtime.h>
#include <hip/hip_bf16.h>
#include <stdint.h>

// Problem constants (fixed by the reference)
#define NROW 2048
#define HDIM 1024
#define VOC  50304
#define KCL  16
#define CDIM 3144   // VOC / KCL

// Tail-GEMM tiling: 64x256 tile, BK=32 (one MFMA k-step), 16 MFMA/wave-iter
#define MT 64
#define NT 256
#define BK 32
#define NCT 13        // ceil(3144/256)
#define MAXTILES 48   // sum ceil(Mk/64) <= 2048/64 + 16 = 48

// Workspace layout in 4-byte units
#define WS_SUMEXP 0            // float[2048] (zeroed each call)
#define WS_COUNTS 2048         // int[16]     (zeroed each call)
#define WS_PART   2064         // float[2048]
#define WS_ZTGT   4112         // float[2048]
#define WS_TCOL   6160         // int[2048]
#define WS_ROWS   8208         // int[16*2048]
#define WS_NTILE  40976        // int
#define WS_TILES  40977        // int[2*48]
#define WS_XB     65536        // bf16[2048][1024]
#define WS_BT     (65536 + 1048576)  // bf16[50304][1024]

typedef unsigned short u16;
typedef __attribute__((ext_vector_type(8))) short short8;
typedef __attribute__((ext_vector_type(4))) float f32x4;
typedef __attribute__((ext_vector_type(4))) unsigned short ushort4v;

__device__ __forceinline__ ushort2 f2bf2(float a, float b) {
    union { __hip_bfloat162 h; ushort2 u; } cv;
    cv.h = __float22bfloat162_rn(float2{a, b});
    return cv.u;
}

// async global->LDS, 16B/lane; LDS dest = wave-uniform base + lane*16
__device__ __forceinline__ void gload16(const void* g, void* lds) {
    __builtin_amdgcn_global_load_lds(
        (__attribute__((address_space(1))) void*)(g),
        (__attribute__((address_space(3))) void*)(lds), 16, 0, 0);
}

// ---------------------------------------------------------------------------
// Kernel 1: bucket rows by cluster, record target within-cluster column
// ---------------------------------------------------------------------------
__global__ void scatter_kernel(const int* __restrict__ y,
                               const int* __restrict__ y_pos,
                               const int* __restrict__ tip,
                               int* ws_i) {
    int n = blockIdx.x * 256 + threadIdx.x;
    if (n >= NROW) return;
    int kn = y_pos[n];
    int slot = atomicAdd(&ws_i[WS_COUNTS + kn], 1);
    ws_i[WS_ROWS + kn * NROW + slot] = n;
    ws_i[WS_TCOL + n] = tip[kn * VOC + y[n]];
}

// ---------------------------------------------------------------------------
// Kernel 1b: build compacted (cluster, row-tile) work list
// ---------------------------------------------------------------------------
__global__ void plan_kernel(int* ws_i) {
    if (threadIdx.x == 0) {
        int t = 0;
        for (int k = 0; k < KCL; k++) {
            int mk = ws_i[WS_COUNTS + k];
            int nt = (mk + MT - 1) / MT;
            for (int r = 0; r < nt; r++) {
                ws_i[WS_TILES + 2 * t]     = k;
                ws_i[WS_TILES + 2 * t + 1] = r;
                t++;
            }
        }
        ws_i[WS_NTILE] = t;
    }
}

// ---------------------------------------------------------------------------
// Kernel 2: cluster logsumexp part (fp32, tiny). One wave per row.
// ---------------------------------------------------------------------------
__global__ void cluster_kernel(const float* __restrict__ x,
                               const float* __restrict__ cw,
                               const int* __restrict__ y_pos,
                               float* ws_f) {
    int wave = threadIdx.x >> 6;
    int lane = threadIdx.x & 63;
    int n = blockIdx.x * 4 + wave;
    float acc[KCL];
#pragma unroll
    for (int k = 0; k < KCL; k++) acc[k] = 0.f;
#pragma unroll
    for (int j = 0; j < 16; j++) {
        int h = j * 64 + lane;
        float xv = x[(size_t)n * HDIM + h];
        const float4* cwr = (const float4*)(cw + (size_t)h * KCL);
#pragma unroll
        for (int q = 0; q < 4; q++) {
            float4 w = cwr[q];
            acc[q * 4 + 0] += xv * w.x;
            acc[q * 4 + 1] += xv * w.y;
            acc[q * 4 + 2] += xv * w.z;
            acc[q * 4 + 3] += xv * w.w;
        }
    }
#pragma unroll
    for (int off = 32; off >= 1; off >>= 1) {
#pragma unroll
        for (int k = 0; k < KCL; k++) acc[k] += __shfl_down(acc[k], off);
    }
    if (lane == 0) {
        int kn = y_pos[n];
        float m = acc[0];
#pragma unroll
        for (int k = 1; k < KCL; k++) m = fmaxf(m, acc[k]);
        float s = 0.f, skn = 0.f;
#pragma unroll
        for (int k = 0; k < KCL; k++) {
            s += __expf(acc[k] - m);
            skn = (k == kn) ? acc[k] : skn;
        }
        ws_f[WS_PART + n] = (m + __logf(s)) - skn;
    }
}

// ---------------------------------------------------------------------------
// Kernel 3a: x fp32 [N][H] -> bf16 [N][H]
// ---------------------------------------------------------------------------
__global__ void convx_kernel(const float* __restrict__ x, u16* __restrict__ xb) {
    int t = blockIdx.x * 256 + threadIdx.x;
    float4 f = ((const float4*)x)[t];
    ushort2 a = f2bf2(f.x, f.y);
    ushort2 b = f2bf2(f.z, f.w);
    ushort4v v = {a.x, a.y, b.x, b.y};
    *(ushort4v*)(xb + (size_t)t * 4) = v;
}

// ---------------------------------------------------------------------------
// Kernel 3b: logits fp32 [H][V] -> Bt bf16 [V][H]
// fp32 LDS tile 64v x 128h, padded stride 129 (byte-stride 516: word stride
// ≡ 1 mod 32 -> both phases are 2-way bank accesses = free per m136).
// ---------------------------------------------------------------------------
#define TV 64
#define TH 128
#define THP 129
__global__ void transpose_kernel(const float* __restrict__ L, u16* __restrict__ Bt) {
    __shared__ float Ls[TV * THP];   // 33 KB
    const int v0 = blockIdx.x * TV;
    const int h0 = blockIdx.y * TH;
    const int t  = threadIdx.x;
    {
        const int vi  = (t & 15) * 4;   // 16 lanes cover 64 v (float4)
        const int hh0 = t >> 4;         // 16 h rows per pass
#pragma unroll
        for (int p = 0; p < 8; p++) {
            int hh = hh0 + p * 16;
            float4 f = *(const float4*)(L + (size_t)(h0 + hh) * VOC + v0 + vi);
            // bank = (4i + hh + j) % 32 -> 2 lanes/bank: free
            Ls[(vi + 0) * THP + hh] = f.x;
            Ls[(vi + 1) * THP + hh] = f.y;
            Ls[(vi + 2) * THP + hh] = f.z;
            Ls[(vi + 3) * THP + hh] = f.w;
        }
    }
    __syncthreads();
    {
        const int i  = t & 15;          // 16 lanes cover 64 h per q-half
        const int vq = t >> 4;          // 16 v rows per pass
#pragma unroll
        for (int p = 0; p < 4; p++) {
#pragma unroll
            for (int q = 0; q < 2; q++) {
                int v  = vq + p * 16;
                int h4 = i * 4 + q * 64;
                // start bank = (v + 4i) % 32 -> 2-way: free
                f32x4 f = *(const f32x4*)&Ls[v * THP + h4];
                ushort2 a = f2bf2(f[0], f[1]);
                ushort2 b = f2bf2(f[2], f[3]);
                ushort4v u = {a.x, a.y, b.x, b.y};
                // 16 lanes x 8B = 128B contiguous per v-row
                *(ushort4v*)(Bt + (size_t)(v0 + v) * HDIM + h0 + h4) = u;
            }
        }
    }
}

// ---------------------------------------------------------------------------
// Kernel 4: tail GEMM, m97 structure. Tile 64x256, bf16 MFMA 16x16x32,
// global_load_lds(16B) staging; 16 MFMA per wave-iter between barriers.
// ---------------------------------------------------------------------------
__launch_bounds__(256)
__global__ void tail_kernel(const u16* __restrict__ xb,
                            const u16* __restrict__ Bt,
                            const int* ws_i, float* ws_f) {
    __shared__ __align__(16) u16 As[MT * BK];   //  4 KB [row][k]
    __shared__ __align__(16) u16 Bs[NT * BK];   // 16 KB [col][k]
    __shared__ int   lrow[MT];
    __shared__ int   ltcol[MT];
    __shared__ float rowsum[MT];

    const int ntile = ws_i[WS_NTILE];
    if ((int)blockIdx.y >= ntile) return;
    const int kcl = ws_i[WS_TILES + 2 * blockIdx.y];
    const int rt  = ws_i[WS_TILES + 2 * blockIdx.y + 1];
    const int ct  = blockIdx.x;
    const int Mk  = ws_i[WS_COUNTS + kcl];

    const int tid = threadIdx.x;
    if (tid < MT) {
        int r = rt * MT + tid;
        int rid = (r < Mk) ? ws_i[WS_ROWS + kcl * NROW + r] : -1;
        lrow[tid]  = rid;
        ltcol[tid] = (rid >= 0) ? ws_i[WS_TCOL + rid] : -1;
        rowsum[tid] = 0.f;
    }
    __syncthreads();

    const int w    = tid >> 6;
    const int l    = tid & 63;
    const int quad = l >> 4;
    const int lm   = l & 15;

    // A staging: wave w stages rows [16w,16w+16): lane -> row 16w+(l>>2)
    int rid_s = lrow[w * 16 + (l >> 2)];
    if (rid_s < 0) rid_s = 0;                       // masked in epilogue
    const u16* agp = xb + (size_t)rid_s * HDIM + (l & 3) * 8;
    char* alds = (char*)As + w * 1024;
    // B staging: 4 instrs/thread; instr j covers cols [j*64, j*64+64)
    const u16* bgp[4];
    char* blds[4];
#pragma unroll
    for (int j = 0; j < 4; j++) {
        int col = j * 64 + w * 16 + (l >> 2);
        int g = ct * NT + col;
        if (g >= CDIM) g = CDIM - 1;                // clamp last col tile
        bgp[j]  = Bt + (size_t)(kcl * CDIM + g) * HDIM + (l & 3) * 8;
        blds[j] = (char*)Bs + j * 4096 + w * 1024;
    }

    f32x4 acc[4][4];
#pragma unroll
    for (int mi = 0; mi < 4; mi++)
#pragma unroll
        for (int ni = 0; ni < 4; ni++) acc[mi][ni] = (f32x4)(0.f);

    for (int h0 = 0; h0 < HDIM; h0 += BK) {
        gload16(agp, alds);
        agp += BK;
#pragma unroll
        for (int j = 0; j < 4; j++) {
            gload16(bgp[j], blds[j]);
            bgp[j] += BK;
        }
        __syncthreads();   // drains vmcnt -> LDS tiles valid

        short8 a[4], b[4];
#pragma unroll
        for (int mi = 0; mi < 4; mi++)
            a[mi] = *(const short8*)&As[(mi * 16 + lm) * BK + quad * 8];
#pragma unroll
        for (int ni = 0; ni < 4; ni++)
            b[ni] = *(const short8*)&Bs[(w * 64 + ni * 16 + lm) * BK + quad * 8];
#pragma unroll
        for (int mi = 0; mi < 4; mi++)
#pragma unroll
            for (int ni = 0; ni < 4; ni++)
                acc[mi][ni] = __builtin_amdgcn_mfma_f32_16x16x32_bf16(
                    a[mi], b[ni], acc[mi][ni], 0, 0, 0);
        __syncthreads();   // frag reads done before next iter's staging
    }

    // epilogue: C/D layout col=lane&15, row=(lane>>4)*4+reg [m89-verified]
#pragma unroll
    for (int mi = 0; mi < 4; mi++) {
#pragma unroll
        for (int r = 0; r < 4; r++) {
            int row_local = mi * 16 + quad * 4 + r;
            int rid = lrow[row_local];
            int tc  = ltcol[row_local];
            float s = 0.f;
#pragma unroll
            for (int ni = 0; ni < 4; ni++) {
                int cl = ct * NT + w * 64 + ni * 16 + lm;
                float z = acc[mi][ni][r];
                if (rid >= 0 && cl < CDIM) {
                    s += __expf(z);
                    if (cl == tc) ws_f[WS_ZTGT + rid] = z;
                }
            }
            s += __shfl_xor(s, 1);
            s += __shfl_xor(s, 2);
            s += __shfl_xor(s, 4);
            s += __shfl_xor(s, 8);
            if (lm == 0 && rid >= 0) atomicAdd(&rowsum[row_local], s);
        }
    }
    __syncthreads();
    if (tid < MT) {
        int rid = lrow[tid];
        if (rid >= 0) atomicAdd(&ws_f[WS_SUMEXP + rid], rowsum[tid]);
    }
}

// ---------------------------------------------------------------------------
// Kernel 5: nll[n] = part[n] + log(sumexp[n]) - z_target[n]
// ---------------------------------------------------------------------------
__global__ void finalize_kernel(const float* ws_f, float* __restrict__ out) {
    int n = blockIdx.x * 256 + threadIdx.x;
    if (n >= NROW) return;
    out[n] = ws_f[WS_PART + n] + __logf(ws_f[WS_SUMEXP + n]) - ws_f[WS_ZTGT + n];
}

// ---------------------------------------------------------------------------
extern "C" void kernel_launch(void* const* d_in, const int* in_sizes, int n_in,
                              void* d_out, int out_size, void* d_ws, size_t ws_size,
                              hipStream_t stream) {
    const float* x      = (const float*)d_in[0];
    const int*   y      = (const int*)d_in[1];
    const int*   y_pos  = (const int*)d_in[2];
    // d_in[3] (pos2token) is the identity partition; unused.
    const int*   tip    = (const int*)d_in[4];
    const float* cw     = (const float*)d_in[5];
    const float* logits = (const float*)d_in[6];
    float* out  = (float*)d_out;
    float* ws_f = (float*)d_ws;
    int*   ws_i = (int*)d_ws;
    u16*   xb   = (u16*)((float*)d_ws + WS_XB);
    u16*   Bt   = (u16*)((float*)d_ws + WS_BT);

    hipMemsetAsync(d_ws, 0, (size_t)(NROW + KCL) * 4, stream);

    scatter_kernel<<<NROW / 256, 256, 0, stream>>>(y, y_pos, tip, ws_i);
    plan_kernel<<<1, 64, 0, stream>>>(ws_i);
    cluster_kernel<<<NROW / 4, 256, 0, stream>>>(x, cw, y_pos, ws_f);
    convx_kernel<<<NROW * HDIM / 4 / 256, 256, 0, stream>>>(x, xb);
    transpose_kernel<<<dim3(VOC / TV, HDIM / TH), 256, 0, stream>>>(logits, Bt);

    dim3 grid(NCT, MAXTILES);   // 13 x 48
    tail_kernel<<<grid, 256, 0, stream>>>(xb, Bt, ws_i, ws_f);

    finalize_kernel<<<NROW / 256, 256, 0, stream>>>(ws_f, out);
}

// Round 4
// 345.369 us; speedup vs baseline: 1.1431x; 1.1294x over previous
//
#include <hip/hip_runtime.h>
#include <hip/hip_bf16.h>
#include <stdint.h>

// Problem constants (fixed by the reference)
#define NROW 2048
#define HDIM 1024
#define VOC  50304
#define KCL  16
#define CDIM 3144   // VOC / KCL

// Tail-GEMM tiling: 64x256 tile, BK=32, 16 MFMA/wave-iter, PK=36 pad
#define MT 64
#define NT 256
#define BK 32
#define PK 36         // u16 stride: 72 B = 18 words -> b64 ops bank-optimal
#define NCT 13        // ceil(3144/256)
#define MAXTILES 48   // sum ceil(Mk/64) <= 2048/64 + 16

// Workspace layout in 4-byte units
#define WS_SUMEXP 0            // float[2048] (zeroed each call)
#define WS_COUNTS 2048         // int[16]     (zeroed each call)
#define WS_PART   2064         // float[2048]
#define WS_ZTGT   4112         // float[2048]
#define WS_TCOL   6160         // int[2048]
#define WS_ROWS   8208         // int[16*2048]
#define WS_NTILE  40976        // int
#define WS_TILES  40977        // int[2*48]

typedef unsigned short u16;
typedef __attribute__((ext_vector_type(8))) short short8;
typedef __attribute__((ext_vector_type(4))) short short4v;
typedef __attribute__((ext_vector_type(4))) float f32x4;
typedef __attribute__((ext_vector_type(4))) unsigned short ushort4v;

__device__ __forceinline__ ushort2 f2bf2(float a, float b) {
    union { __hip_bfloat162 h; ushort2 u; } cv;
    cv.h = __float22bfloat162_rn(float2{a, b});
    return cv.u;
}

// ---------------------------------------------------------------------------
// Kernel 1: bucket rows by cluster, record target within-cluster column
// ---------------------------------------------------------------------------
__global__ void scatter_kernel(const int* __restrict__ y,
                               const int* __restrict__ y_pos,
                               const int* __restrict__ tip,
                               int* ws_i) {
    int n = blockIdx.x * 256 + threadIdx.x;
    if (n >= NROW) return;
    int kn = y_pos[n];
    int slot = atomicAdd(&ws_i[WS_COUNTS + kn], 1);
    ws_i[WS_ROWS + kn * NROW + slot] = n;
    ws_i[WS_TCOL + n] = tip[kn * VOC + y[n]];
}

// ---------------------------------------------------------------------------
// Kernel 1b: build compacted (cluster, row-tile) list — one wave, shfl scan
// ---------------------------------------------------------------------------
__global__ void plan_kernel(int* ws_i) {
    int lane = threadIdx.x;
    int nt = (lane < KCL) ? (ws_i[WS_COUNTS + lane] + MT - 1) / MT : 0;
    int pre = nt;
#pragma unroll
    for (int off = 1; off < 16; off <<= 1) {
        int v = __shfl_up(pre, off);
        if ((lane & 15) >= off) pre += v;
    }
    int start = pre - nt;
    if (lane < KCL) {
        for (int r = 0; r < nt; r++) {
            ws_i[WS_TILES + 2 * (start + r)]     = lane;
            ws_i[WS_TILES + 2 * (start + r) + 1] = r;
        }
        if (lane == KCL - 1) ws_i[WS_NTILE] = start + nt;
    }
}

// ---------------------------------------------------------------------------
// Kernel 2: cluster logsumexp part (fp32, tiny). One wave per row.
// ---------------------------------------------------------------------------
__global__ void cluster_kernel(const float* __restrict__ x,
                               const float* __restrict__ cw,
                               const int* __restrict__ y_pos,
                               float* ws_f) {
    int wave = threadIdx.x >> 6;
    int lane = threadIdx.x & 63;
    int n = blockIdx.x * 4 + wave;
    float acc[KCL];
#pragma unroll
    for (int k = 0; k < KCL; k++) acc[k] = 0.f;
#pragma unroll
    for (int j = 0; j < 16; j++) {
        int h = j * 64 + lane;
        float xv = x[(size_t)n * HDIM + h];
        const float4* cwr = (const float4*)(cw + (size_t)h * KCL);
#pragma unroll
        for (int q = 0; q < 4; q++) {
            float4 w = cwr[q];
            acc[q * 4 + 0] += xv * w.x;
            acc[q * 4 + 1] += xv * w.y;
            acc[q * 4 + 2] += xv * w.z;
            acc[q * 4 + 3] += xv * w.w;
        }
    }
#pragma unroll
    for (int off = 32; off >= 1; off >>= 1) {
#pragma unroll
        for (int k = 0; k < KCL; k++) acc[k] += __shfl_down(acc[k], off);
    }
    if (lane == 0) {
        int kn = y_pos[n];
        float m = acc[0];
#pragma unroll
        for (int k = 1; k < KCL; k++) m = fmaxf(m, acc[k]);
        float s = 0.f, skn = 0.f;
#pragma unroll
        for (int k = 0; k < KCL; k++) {
            s += __expf(acc[k] - m);
            skn = (k == kn) ? acc[k] : skn;
        }
        ws_f[WS_PART + n] = (m + __logf(s)) - skn;
    }
}

// ---------------------------------------------------------------------------
// Kernel 3: tail GEMM, direct fp32 reads + in-register cvt, reg-pipelined.
// Tile 64x256, bf16 MFMA 16x16x32, PK=36 LDS padding (b64 bank-optimal).
// ---------------------------------------------------------------------------
__launch_bounds__(256)
__global__ void tail_kernel(const float* __restrict__ x,
                            const float* __restrict__ logits,
                            const int* ws_i, float* ws_f) {
    __shared__ __align__(16) u16 As[MT * PK];   // 4.5 KB [row][k]
    __shared__ __align__(16) u16 Bs[NT * PK];   // 18  KB [col][k]
    __shared__ int   lrow[MT];
    __shared__ int   ltcol[MT];
    __shared__ float rowsum[MT];

    const int ntile = ws_i[WS_NTILE];
    if ((int)blockIdx.y >= ntile) return;
    const int kcl = ws_i[WS_TILES + 2 * blockIdx.y];
    const int rt  = ws_i[WS_TILES + 2 * blockIdx.y + 1];
    const int ct  = blockIdx.x;
    const int Mk  = ws_i[WS_COUNTS + kcl];

    const int tid = threadIdx.x;
    if (tid < MT) {
        int r = rt * MT + tid;
        int rid = (r < Mk) ? ws_i[WS_ROWS + kcl * NROW + r] : -1;
        lrow[tid]  = rid;
        ltcol[tid] = (rid >= 0) ? ws_i[WS_TCOL + rid] : -1;
        rowsum[tid] = 0.f;
    }
    __syncthreads();

    const int w    = tid >> 6;
    const int l    = tid & 63;
    const int quad = l >> 4;
    const int lm   = l & 15;

    // --- staging maps ---
    // A: thread t -> row t>>2, k-chunk (t&3)*8 (8 fp32 -> 8 bf16)
    const int arow = tid >> 2;
    const int ak0  = (tid & 3) * 8;
    int rid_s = lrow[arow]; if (rid_s < 0) rid_s = 0;   // masked in epilogue
    const float* ap = x + (size_t)rid_s * HDIM + ak0;
    // B: thread t -> col t, all 32 k (scalar loads; lanes = consecutive cols
    // -> 256 B-per-instr coalescing; pos2token is the identity partition)
    int gc = ct * NT + tid; if (gc >= CDIM) gc = CDIM - 1;
    const float* bp = logits + (size_t)(kcl * CDIM + gc);

    float ar[8];
    float br[BK];
    // prologue: loads for h0 = 0
#pragma unroll
    for (int j = 0; j < 8; j++) ar[j] = ap[j];
#pragma unroll
    for (int k = 0; k < BK; k++) br[k] = bp[(size_t)k * VOC];
    ap += BK;
    bp += (size_t)BK * VOC;

    f32x4 acc[4][4];
#pragma unroll
    for (int mi = 0; mi < 4; mi++)
#pragma unroll
        for (int ni = 0; ni < 4; ni++) acc[mi][ni] = (f32x4)(0.f);

    union fr { short4v h[2]; short8 s; };

    for (int h0 = 0; h0 < HDIM; h0 += BK) {
        // ---- cvt staged registers -> LDS (bf16) ----
#pragma unroll
        for (int jj = 0; jj < 2; jj++) {
            ushort2 p0 = f2bf2(ar[jj * 4 + 0], ar[jj * 4 + 1]);
            ushort2 p1 = f2bf2(ar[jj * 4 + 2], ar[jj * 4 + 3]);
            ushort4v v = {p0.x, p0.y, p1.x, p1.y};
            *(ushort4v*)&As[arow * PK + ak0 + jj * 4] = v;
        }
#pragma unroll
        for (int j = 0; j < 8; j++) {
            ushort2 p0 = f2bf2(br[j * 4 + 0], br[j * 4 + 1]);
            ushort2 p1 = f2bf2(br[j * 4 + 2], br[j * 4 + 3]);
            ushort4v v = {p0.x, p0.y, p1.x, p1.y};
            *(ushort4v*)&Bs[tid * PK + j * 4] = v;
        }
        __syncthreads();

        // ---- issue next iter's global loads; drain under MFMA phase ----
        if (h0 + BK < HDIM) {
#pragma unroll
            for (int j = 0; j < 8; j++) ar[j] = ap[j];
#pragma unroll
            for (int k = 0; k < BK; k++) br[k] = bp[(size_t)k * VOC];
            ap += BK;
            bp += (size_t)BK * VOC;
        }

        // ---- fragments + MFMA ----
        short8 a[4], b[4];
#pragma unroll
        for (int mi = 0; mi < 4; mi++) {
            fr f;
            const short4v* p = (const short4v*)&As[(mi * 16 + lm) * PK + quad * 8];
            f.h[0] = p[0]; f.h[1] = p[1];
            a[mi] = f.s;
        }
#pragma unroll
        for (int ni = 0; ni < 4; ni++) {
            fr f;
            const short4v* p = (const short4v*)&Bs[(w * 64 + ni * 16 + lm) * PK + quad * 8];
            f.h[0] = p[0]; f.h[1] = p[1];
            b[ni] = f.s;
        }
#pragma unroll
        for (int mi = 0; mi < 4; mi++)
#pragma unroll
            for (int ni = 0; ni < 4; ni++)
                acc[mi][ni] = __builtin_amdgcn_mfma_f32_16x16x32_bf16(
                    a[mi], b[ni], acc[mi][ni], 0, 0, 0);
        __syncthreads();
    }

    // epilogue: C/D layout col=lane&15, row=(lane>>4)*4+reg [m89-verified]
#pragma unroll
    for (int mi = 0; mi < 4; mi++) {
#pragma unroll
        for (int r = 0; r < 4; r++) {
            int row_local = mi * 16 + quad * 4 + r;
            int rid = lrow[row_local];
            int tc  = ltcol[row_local];
            float s = 0.f;
#pragma unroll
            for (int ni = 0; ni < 4; ni++) {
                int cl = ct * NT + w * 64 + ni * 16 + lm;
                float z = acc[mi][ni][r];
                if (rid >= 0 && cl < CDIM) {
                    s += __expf(z);
                    if (cl == tc) ws_f[WS_ZTGT + rid] = z;
                }
            }
            s += __shfl_xor(s, 1);
            s += __shfl_xor(s, 2);
            s += __shfl_xor(s, 4);
            s += __shfl_xor(s, 8);
            if (lm == 0 && rid >= 0) atomicAdd(&rowsum[row_local], s);
        }
    }
    __syncthreads();
    if (tid < MT) {
        int rid = lrow[tid];
        if (rid >= 0) atomicAdd(&ws_f[WS_SUMEXP + rid], rowsum[tid]);
    }
}

// ---------------------------------------------------------------------------
// Kernel 4: nll[n] = part[n] + log(sumexp[n]) - z_target[n]
// ---------------------------------------------------------------------------
__global__ void finalize_kernel(const float* ws_f, float* __restrict__ out) {
    int n = blockIdx.x * 256 + threadIdx.x;
    if (n >= NROW) return;
    out[n] = ws_f[WS_PART + n] + __logf(ws_f[WS_SUMEXP + n]) - ws_f[WS_ZTGT + n];
}

// ---------------------------------------------------------------------------
extern "C" void kernel_launch(void* const* d_in, const int* in_sizes, int n_in,
                              void* d_out, int out_size, void* d_ws, size_t ws_size,
                              hipStream_t stream) {
    const float* x      = (const float*)d_in[0];
    const int*   y      = (const int*)d_in[1];
    const int*   y_pos  = (const int*)d_in[2];
    // d_in[3] (pos2token) is the identity partition; unused.
    const int*   tip    = (const int*)d_in[4];
    const float* cw     = (const float*)d_in[5];
    const float* logits = (const float*)d_in[6];
    float* out  = (float*)d_out;
    float* ws_f = (float*)d_ws;
    int*   ws_i = (int*)d_ws;

    hipMemsetAsync(d_ws, 0, (size_t)(NROW + KCL) * 4, stream);

    scatter_kernel<<<NROW / 256, 256, 0, stream>>>(y, y_pos, tip, ws_i);
    plan_kernel<<<1, 64, 0, stream>>>(ws_i);
    cluster_kernel<<<NROW / 4, 256, 0, stream>>>(x, cw, y_pos, ws_f);

    dim3 grid(NCT, MAXTILES);   // 13 x 48
    tail_kernel<<<grid, 256, 0, stream>>>(x, logits, ws_i, ws_f);

    finalize_kernel<<<NROW / 256, 256, 0, stream>>>(ws_f, out);
}